// Round 19
// baseline (296.847 us; speedup 1.0000x reference)
//
#include <hip/hip_runtime.h>

#define N_ROWS 32768
#define D_DIM  512
#define P_DIM  4096

#define OUT_LOGITS (32768LL * 512)
#define OUT_CVAE   (OUT_LOGITS + 32768LL * 4096)
#define OUT_PROT   (OUT_CVAE + 1)

typedef __attribute__((ext_vector_type(8))) short short8;
typedef __attribute__((ext_vector_type(4))) float f32x4;

__device__ __forceinline__ unsigned short f2bf(float f) {
  unsigned u = __float_as_uint(f);
  u = (u + 0x7FFFu + ((u >> 16) & 1u)) >> 16;
  return (unsigned short)u;
}

__device__ __forceinline__ void gload16(const void* g, void* l) {
  __builtin_amdgcn_global_load_lds((const __attribute__((address_space(1))) void*)g,
                                   (__attribute__((address_space(3))) void*)l,
                                   16, 0, 0);
}

// ---------------------------------------------------------------------------
// Combined prep, ONE launch: blocks [0,8192) = X path (L2-norm, xn NT stores,
// bf16 fragment-major, min-array init on first 144 blocks); blocks
// [8192,9216) = W path (|row|^2 + bf16 fragment-major). Layout identical to
// R13/R18 (verified).
// ---------------------------------------------------------------------------
__global__ __launch_bounds__(256) void prep_kernel(const float* __restrict__ x,
                                                   const float* __restrict__ W,
                                                   float* __restrict__ xn,
                                                   unsigned short* __restrict__ Xbf,
                                                   unsigned short* __restrict__ Wbf,
                                                   float* __restrict__ w2,
                                                   unsigned int* __restrict__ rmg,
                                                   unsigned int* __restrict__ cmg) {
  const int bid = blockIdx.x;
  const int isX = (bid < 8192);
  if (isX) {
    if (bid < 128)      rmg[bid * 256 + threadIdx.x] = 0x7F800000u;
    else if (bid < 144) cmg[(bid - 128) * 256 + threadIdx.x] = 0x7F800000u;
  }
  int wave = threadIdx.x >> 6, lane = threadIdx.x & 63;
  int row  = (isX ? bid : (bid - 8192)) * 4 + wave;
  const float* p = (isX ? x : W) + (size_t)row * D_DIM + lane * 8;
  float4 v0 = *(const float4*)p;
  float4 v1 = *(const float4*)(p + 4);
  float ss = v0.x*v0.x + v0.y*v0.y + v0.z*v0.z + v0.w*v0.w
           + v1.x*v1.x + v1.y*v1.y + v1.z*v1.z + v1.w*v1.w;
#pragma unroll
  for (int m = 1; m < 64; m <<= 1) ss += __shfl_xor(ss, m);
  if (isX) {
    float rinv = 1.0f / fmaxf(sqrtf(ss), 1e-12f);
    v0.x *= rinv; v0.y *= rinv; v0.z *= rinv; v0.w *= rinv;
    v1.x *= rinv; v1.y *= rinv; v1.z *= rinv; v1.w *= rinv;
    f32x4* qp = (f32x4*)(xn + (size_t)row * D_DIM + lane * 8);
    f32x4 a0 = {v0.x, v0.y, v0.z, v0.w};
    f32x4 a1 = {v1.x, v1.y, v1.z, v1.w};
    __builtin_nontemporal_store(a0, qp);
    __builtin_nontemporal_store(a1, qp + 1);
  } else {
    if (lane == 0) w2[row] = ss;
  }
  uint4 b;
  b.x = (unsigned)f2bf(v0.x) | ((unsigned)f2bf(v0.y) << 16);
  b.y = (unsigned)f2bf(v0.z) | ((unsigned)f2bf(v0.w) << 16);
  b.z = (unsigned)f2bf(v1.x) | ((unsigned)f2bf(v1.y) << 16);
  b.w = (unsigned)f2bf(v1.z) | ((unsigned)f2bf(v1.w) << 16);
  int tile = row >> 7, fr = (row >> 4) & 7, r = row & 15;
  size_t dst = (size_t)(tile * 16 + (lane >> 2)) * 4096
             + (size_t)((fr * 64 + (lane & 3) * 16 + r) * 8);
  *(uint4*)((isX ? Xbf : Wbf) + dst) = b;
}

// ---------------------------------------------------------------------------
// 128x128-tile GEMM — R18 verbatim EXCEPT logits stores are now CACHED
// (default) instead of non-temporal. Theory: NT forced 64 B granules to
// DRAM scattered over 16 x 16KB-strided rows (page thrash, ~2.5 TB/s eff);
// cached stores let L2 write-combine into full-line writebacks.
// W-frags direct from L2; X 3-buffered (3 x 8 KB) with counted vmcnt(2);
// 4 blocks/CU; one s_barrier per step; setprio; fused d2 -> global atomicMin.
// ---------------------------------------------------------------------------
__global__ __launch_bounds__(256, 4) void gemm_fused(
    const unsigned short* __restrict__ Wb, const unsigned short* __restrict__ Xb,
    const float* __restrict__ w2, float* __restrict__ Cout,
    unsigned int* __restrict__ rowmin_g, unsigned int* __restrict__ colmin_g) {
  __shared__ __align__(16) unsigned short SB[3][4096];   // x tile 128x32, 3-buf
  __shared__ unsigned int rowmin_u[128];                 // per x-row
  __shared__ unsigned int colmin_u[128];                 // per w-col

  const int tid = threadIdx.x;
  const int wave = tid >> 6, lane = tid & 63;
  const int q = lane >> 4, r16 = lane & 15;
  const int ww = wave >> 1, wx = wave & 1;

  const int b = blockIdx.x;
  const int tw = (b & 7) * 4 + ((b >> 3) & 3);   // 0..31 (XCD-pinned W column)
  const int tx = b >> 5;                         // 0..255
  const int w0 = tw * 128, x0 = tx * 128;

  if (tid < 128) { rowmin_u[tid] = 0x7F800000u; colmin_u[tid] = 0x7F800000u; }

  const unsigned short* Wg = Wb + (size_t)(tw * 16) * 4096;
  const unsigned short* Xg = Xb + (size_t)(tx * 16) * 4096;

  f32x4 acc[4][4];
#pragma unroll
  for (int m = 0; m < 4; ++m)
#pragma unroll
    for (int n = 0; n < 4; ++n) acc[m][n] = (f32x4){0.f, 0.f, 0.f, 0.f};

  auto stg = [&](int kt, int bu) {   // 2 gload_lds per thread (X only, 8 KB)
#pragma unroll
    for (int i = 0; i < 2; ++i) {
      int c = (tid + 256 * i) * 8;
      gload16(Xg + (size_t)kt * 4096 + c, &SB[bu][0] + c);
    }
  };

  stg(0, 0);
  stg(1, 1);

#pragma unroll
  for (int kt = 0; kt < 16; ++kt) {
    const int cur = kt % 3;
    if (kt < 15) { asm volatile("s_waitcnt vmcnt(2)" ::: "memory"); }   // stg(kt) done
    else         { asm volatile("s_waitcnt vmcnt(0)" ::: "memory"); }
    __builtin_amdgcn_s_barrier();

    if (kt < 14) stg(kt + 2, (kt + 2) % 3);   // buffer last read at kt-1: WAR-safe

    short8 af[4], bf[4];
#pragma unroll
    for (int m = 0; m < 4; ++m)          // W-frags straight from L1/L2
      af[m] = *(const short8*)(Wg + (size_t)kt * 4096 + ((ww * 4 + m) * 64 + lane) * 8);
#pragma unroll
    for (int n = 0; n < 4; ++n)
      bf[n] = *(const short8*)(&SB[cur][0] + ((wx * 4 + n) * 64 + lane) * 8);

    __builtin_amdgcn_s_setprio(1);
#pragma unroll
    for (int m = 0; m < 4; ++m)
#pragma unroll
      for (int n = 0; n < 4; ++n)
        acc[m][n] = __builtin_amdgcn_mfma_f32_16x16x32_bf16(af[m], bf[n], acc[m][n], 0, 0, 0);
    __builtin_amdgcn_s_setprio(0);
  }

  // ---- epilogue: CACHED float4 stores + fused d2 mins ----
  float rmin[4];                      // per n (x-rows)
  float cmin[4][4];                   // per m,j (w-cols)
#pragma unroll
  for (int n = 0; n < 4; ++n) rmin[n] = 1e30f;
#pragma unroll
  for (int m = 0; m < 4; ++m)
#pragma unroll
    for (int j = 0; j < 4; ++j) cmin[m][j] = 1e30f;

  const float* w2p = w2 + w0 + ww * 64;
#pragma unroll
  for (int m = 0; m < 4; ++m) {
    float4 w2v = *(const float4*)(w2p + m * 16 + q * 4);
    const size_t wcol = (size_t)(w0 + ww * 64 + m * 16 + q * 4);
#pragma unroll
    for (int n = 0; n < 4; ++n) {
      f32x4 c = acc[m][n];
      int xr = x0 + wx * 64 + n * 16 + r16;
      *(f32x4*)&Cout[(size_t)xr * P_DIM + wcol] = c;   // cached store
      float d0 = fmaxf(fmaf(-2.f, c[0], 1.f + w2v.x), 0.f);
      float d1 = fmaxf(fmaf(-2.f, c[1], 1.f + w2v.y), 0.f);
      float d2 = fmaxf(fmaf(-2.f, c[2], 1.f + w2v.z), 0.f);
      float d3 = fmaxf(fmaf(-2.f, c[3], 1.f + w2v.w), 0.f);
      rmin[n] = fminf(rmin[n], fminf(fminf(d0, d1), fminf(d2, d3)));
      cmin[m][0] = fminf(cmin[m][0], d0);
      cmin[m][1] = fminf(cmin[m][1], d1);
      cmin[m][2] = fminf(cmin[m][2], d2);
      cmin[m][3] = fminf(cmin[m][3], d3);
    }
  }
  // row-min: reduce across q (same x-row for equal r16)
#pragma unroll
  for (int mask = 16; mask <= 32; mask <<= 1)
#pragma unroll
    for (int n = 0; n < 4; ++n)
      rmin[n] = fminf(rmin[n], __shfl_xor(rmin[n], mask));
  if (q == 0) {
#pragma unroll
    for (int n = 0; n < 4; ++n)
      atomicMin(&rowmin_u[wx * 64 + n * 16 + r16], __float_as_uint(rmin[n]));
  }
  // col-min: reduce across r16 (same w-col for equal q)
#pragma unroll
  for (int mask = 1; mask <= 8; mask <<= 1)
#pragma unroll
    for (int m = 0; m < 4; ++m)
#pragma unroll
      for (int j = 0; j < 4; ++j)
        cmin[m][j] = fminf(cmin[m][j], __shfl_xor(cmin[m][j], mask));
  if (r16 == 0) {
#pragma unroll
    for (int m = 0; m < 4; ++m)
#pragma unroll
      for (int j = 0; j < 4; ++j)
        atomicMin(&colmin_u[ww * 64 + m * 16 + q * 4 + j], __float_as_uint(cmin[m][j]));
  }
  __syncthreads();
  if (tid < 128) atomicMin(&rowmin_g[x0 + tid], rowmin_u[tid]);
  else           atomicMin(&colmin_g[w0 + (tid - 128)], colmin_u[tid - 128]);
}

// ---------------------------------------------------------------------------
// Combined reduce: bid<128 -> row mins chunk; bid>=128 -> col mins chunk.
// sqrt + fixed-order block sums (deterministic).
// ---------------------------------------------------------------------------
__global__ __launch_bounds__(256) void minsqrt_sum(const unsigned int* __restrict__ rmins,
                                                   const unsigned int* __restrict__ cmins,
                                                   float* __restrict__ rowsums,
                                                   float* __restrict__ colsums) {
  int bid = blockIdx.x;
  const unsigned int* src = (bid < 128) ? (rmins + bid * 256) : (cmins + (bid - 128) * 256);
  float s = sqrtf(__uint_as_float(src[threadIdx.x]));
#pragma unroll
  for (int mask = 1; mask < 64; mask <<= 1) s += __shfl_xor(s, mask);
  __shared__ float wsum[4];
  int wave = threadIdx.x >> 6, lane = threadIdx.x & 63;
  if (lane == 0) wsum[wave] = s;
  __syncthreads();
  if (threadIdx.x == 0) {
    float t = wsum[0] + wsum[1] + wsum[2] + wsum[3];
    if (bid < 128) rowsums[bid] = t; else colsums[bid - 128] = t;
  }
}

__global__ void finalize_kernel(const float* __restrict__ rowp, const float* __restrict__ colp,
                                const float* __restrict__ recon, const float* __restrict__ kl,
                                const float* __restrict__ mmd, float* __restrict__ out) {
  int lane = threadIdx.x;  // 64 threads
  float rs = rowp[lane] + rowp[lane + 64];
  float cs = (lane < 16) ? colp[lane] : 0.0f;
#pragma unroll
  for (int mask = 1; mask < 64; mask <<= 1) {
    rs += __shfl_xor(rs, mask);
    cs += __shfl_xor(cs, mask);
  }
  if (lane == 0) {
    out[OUT_CVAE] = recon[0] + 0.5f * kl[0] + mmd[0];
    out[OUT_PROT] = 0.5f * (rs / (float)N_ROWS) + 0.5f * (cs / (float)P_DIM);
  }
}

extern "C" void kernel_launch(void* const* d_in, const int* in_sizes, int n_in,
                              void* d_out, int out_size, void* d_ws, size_t ws_size,
                              hipStream_t stream) {
  const float* x     = (const float*)d_in[0];
  const float* W     = (const float*)d_in[1];
  const float* recon = (const float*)d_in[2];
  const float* kl    = (const float*)d_in[3];
  const float* mmd   = (const float*)d_in[4];
  float* out    = (float*)d_out;
  float* xn     = out;
  float* logits = out + OUT_LOGITS;

  char* ws = (char*)d_ws;
  unsigned short* Xbf = (unsigned short*)ws;                 // 33,554,432 B
  unsigned short* Wbf = (unsigned short*)(ws + 33554432);    //  4,194,304 B
  float* w2          = (float*)(ws + 37748736);              //     16,384 B
  unsigned int* rmg  = (unsigned int*)(ws + 37765120);       //    131,072 B (32768)
  unsigned int* cmg  = (unsigned int*)(ws + 37896192);       //     16,384 B (4096)
  float* rowsums     = (float*)(ws + 37912576);              //        512 B (128)
  float* colsums     = (float*)(ws + 37913088);              //         64 B (16)

  prep_kernel<<<8192 + 1024, 256, 0, stream>>>(x, W, xn, Xbf, Wbf, w2, rmg, cmg);
  gemm_fused<<<(N_ROWS / 128) * (P_DIM / 128), 256, 0, stream>>>(
      Wbf, Xbf, w2, logits, rmg, cmg);
  minsqrt_sum<<<144, 256, 0, stream>>>(rmg, cmg, rowsums, colsums);
  finalize_kernel<<<1, 64, 0, stream>>>(rowsums, colsums, recon, kl, mmd, out);
}

// Round 20
// 267.356 us; speedup vs baseline: 1.1103x; 1.1103x over previous
//
#include <hip/hip_runtime.h>

#define N_ROWS 32768
#define D_DIM  512
#define P_DIM  4096

#define OUT_LOGITS (32768LL * 512)
#define OUT_CVAE   (OUT_LOGITS + 32768LL * 4096)
#define OUT_PROT   (OUT_CVAE + 1)

typedef __attribute__((ext_vector_type(8))) short short8;
typedef __attribute__((ext_vector_type(4))) float f32x4;

__device__ __forceinline__ unsigned short f2bf(float f) {
  unsigned u = __float_as_uint(f);
  u = (u + 0x7FFFu + ((u >> 16) & 1u)) >> 16;
  return (unsigned short)u;
}

__device__ __forceinline__ void gload16(const void* g, void* l) {
  __builtin_amdgcn_global_load_lds((const __attribute__((address_space(1))) void*)g,
                                   (__attribute__((address_space(3))) void*)l,
                                   16, 0, 0);
}

// ---------------------------------------------------------------------------
// Combined prep (R18 verbatim): blocks [0,8192) = X path; [8192,9216) = W.
// bf16 fragment-major 128-row-tile layout; xn NT stores; min-array init.
// ---------------------------------------------------------------------------
__global__ __launch_bounds__(256) void prep_kernel(const float* __restrict__ x,
                                                   const float* __restrict__ W,
                                                   float* __restrict__ xn,
                                                   unsigned short* __restrict__ Xbf,
                                                   unsigned short* __restrict__ Wbf,
                                                   float* __restrict__ w2,
                                                   unsigned int* __restrict__ rmg,
                                                   unsigned int* __restrict__ cmg) {
  const int bid = blockIdx.x;
  const int isX = (bid < 8192);
  if (isX) {
    if (bid < 128)      rmg[bid * 256 + threadIdx.x] = 0x7F800000u;
    else if (bid < 144) cmg[(bid - 128) * 256 + threadIdx.x] = 0x7F800000u;
  }
  int wave = threadIdx.x >> 6, lane = threadIdx.x & 63;
  int row  = (isX ? bid : (bid - 8192)) * 4 + wave;
  const float* p = (isX ? x : W) + (size_t)row * D_DIM + lane * 8;
  float4 v0 = *(const float4*)p;
  float4 v1 = *(const float4*)(p + 4);
  float ss = v0.x*v0.x + v0.y*v0.y + v0.z*v0.z + v0.w*v0.w
           + v1.x*v1.x + v1.y*v1.y + v1.z*v1.z + v1.w*v1.w;
#pragma unroll
  for (int m = 1; m < 64; m <<= 1) ss += __shfl_xor(ss, m);
  if (isX) {
    float rinv = 1.0f / fmaxf(sqrtf(ss), 1e-12f);
    v0.x *= rinv; v0.y *= rinv; v0.z *= rinv; v0.w *= rinv;
    v1.x *= rinv; v1.y *= rinv; v1.z *= rinv; v1.w *= rinv;
    f32x4* qp = (f32x4*)(xn + (size_t)row * D_DIM + lane * 8);
    f32x4 a0 = {v0.x, v0.y, v0.z, v0.w};
    f32x4 a1 = {v1.x, v1.y, v1.z, v1.w};
    __builtin_nontemporal_store(a0, qp);
    __builtin_nontemporal_store(a1, qp + 1);
  } else {
    if (lane == 0) w2[row] = ss;
  }
  uint4 b;
  b.x = (unsigned)f2bf(v0.x) | ((unsigned)f2bf(v0.y) << 16);
  b.y = (unsigned)f2bf(v0.z) | ((unsigned)f2bf(v0.w) << 16);
  b.z = (unsigned)f2bf(v1.x) | ((unsigned)f2bf(v1.y) << 16);
  b.w = (unsigned)f2bf(v1.z) | ((unsigned)f2bf(v1.w) << 16);
  int tile = row >> 7, fr = (row >> 4) & 7, r = row & 15;
  size_t dst = (size_t)(tile * 16 + (lane >> 2)) * 4096
             + (size_t)((fr * 64 + (lane & 3) * 16 + r) * 8);
  *(uint4*)((isX ? Xbf : Wbf) + dst) = b;
}

// ---------------------------------------------------------------------------
// 128x256-tile GEMM (dual W-tile per block): HALVES X re-read traffic
// (1.0 GB L3 -> 0.5 GB), attacking the shared ~7.8 TB/s fabric ceiling that
// five schedule variants all hit. X staged once (3-buf, counted vmcnt(2) —
// R18 verified); BOTH W-subtiles' frags loaded direct from XCD-L2; one X
// LDS read (bf) feeds 2x MFMAs. acc[2][4][4] = 128 f32 -> VGPR ~196,
// launch_bounds(256,2) caps at 256 (no spill), 2 blocks/CU.
// NT scattered stores (best measured). Fused d2 -> global atomicMin.
// ---------------------------------------------------------------------------
__global__ __launch_bounds__(256, 2) void gemm_fused(
    const unsigned short* __restrict__ Wb, const unsigned short* __restrict__ Xb,
    const float* __restrict__ w2, float* __restrict__ Cout,
    unsigned int* __restrict__ rowmin_g, unsigned int* __restrict__ colmin_g) {
  __shared__ __align__(16) unsigned short SB[3][4096];   // x tile 128x32, 3-buf
  __shared__ unsigned int rowmin_u[128];                 // per x-row
  __shared__ unsigned int colmin_u[256];                 // per w-col (2 tiles)

  const int tid = threadIdx.x;
  const int wave = tid >> 6, lane = tid & 63;
  const int q = lane >> 4, r16 = lane & 15;
  const int ww = wave >> 1, wx = wave & 1;

  const int b = blockIdx.x;
  const int twp = (b & 7) * 2 + ((b >> 3) & 1);  // 0..15 (XCD-pinned W pair)
  const int tx = b >> 4;                         // 0..255
  const int w0 = twp * 256, x0 = tx * 128;

  if (tid < 128) rowmin_u[tid] = 0x7F800000u;
  colmin_u[tid] = 0x7F800000u;

  const unsigned short* Wg = Wb + (size_t)(twp * 2) * 65536;  // 2 x 128-tile
  const unsigned short* Xg = Xb + (size_t)tx * 65536;

  f32x4 acc[2][4][4];
#pragma unroll
  for (int t = 0; t < 2; ++t)
#pragma unroll
    for (int m = 0; m < 4; ++m)
#pragma unroll
      for (int n = 0; n < 4; ++n) acc[t][m][n] = (f32x4){0.f, 0.f, 0.f, 0.f};

  auto stg = [&](int kt, int bu) {   // 2 gload_lds per thread (X only, 8 KB)
#pragma unroll
    for (int i = 0; i < 2; ++i) {
      int c = (tid + 256 * i) * 8;
      gload16(Xg + (size_t)kt * 4096 + c, &SB[bu][0] + c);
    }
  };

  stg(0, 0);
  stg(1, 1);

#pragma unroll
  for (int kt = 0; kt < 16; ++kt) {
    const int cur = kt % 3;
    if (kt < 15) { asm volatile("s_waitcnt vmcnt(2)" ::: "memory"); }   // stg(kt) done
    else         { asm volatile("s_waitcnt vmcnt(0)" ::: "memory"); }
    __builtin_amdgcn_s_barrier();

    if (kt < 14) stg(kt + 2, (kt + 2) % 3);   // buffer last read at kt-1: WAR-safe

    short8 af[2][4], bf[4];
#pragma unroll
    for (int t = 0; t < 2; ++t)
#pragma unroll
      for (int m = 0; m < 4; ++m)      // W-frags straight from XCD-L2
        af[t][m] = *(const short8*)(Wg + (size_t)t * 65536 + (size_t)kt * 4096
                                    + ((ww * 4 + m) * 64 + lane) * 8);
#pragma unroll
    for (int n = 0; n < 4; ++n)
      bf[n] = *(const short8*)(&SB[cur][0] + ((wx * 4 + n) * 64 + lane) * 8);

    __builtin_amdgcn_s_setprio(1);
#pragma unroll
    for (int t = 0; t < 2; ++t)
#pragma unroll
      for (int m = 0; m < 4; ++m)
#pragma unroll
        for (int n = 0; n < 4; ++n)
          acc[t][m][n] = __builtin_amdgcn_mfma_f32_16x16x32_bf16(af[t][m], bf[n], acc[t][m][n], 0, 0, 0);
    __builtin_amdgcn_s_setprio(0);
  }

  // ---- epilogue: NT float4 stores + fused d2 mins ----
  float rmin[4];                      // per n (x-rows), min over both W tiles
  float cmin[2][4][4];                // per t,m,j (w-cols)
#pragma unroll
  for (int n = 0; n < 4; ++n) rmin[n] = 1e30f;
#pragma unroll
  for (int t = 0; t < 2; ++t)
#pragma unroll
    for (int m = 0; m < 4; ++m)
#pragma unroll
      for (int j = 0; j < 4; ++j) cmin[t][m][j] = 1e30f;

#pragma unroll
  for (int t = 0; t < 2; ++t) {
    const float* w2p = w2 + w0 + t * 128 + ww * 64;
#pragma unroll
    for (int m = 0; m < 4; ++m) {
      float4 w2v = *(const float4*)(w2p + m * 16 + q * 4);
      const size_t wcol = (size_t)(w0 + t * 128 + ww * 64 + m * 16 + q * 4);
#pragma unroll
      for (int n = 0; n < 4; ++n) {
        f32x4 c = acc[t][m][n];
        int xr = x0 + wx * 64 + n * 16 + r16;
        __builtin_nontemporal_store(c, (f32x4*)&Cout[(size_t)xr * P_DIM + wcol]);
        float d0 = fmaxf(fmaf(-2.f, c[0], 1.f + w2v.x), 0.f);
        float d1 = fmaxf(fmaf(-2.f, c[1], 1.f + w2v.y), 0.f);
        float d2 = fmaxf(fmaf(-2.f, c[2], 1.f + w2v.z), 0.f);
        float d3 = fmaxf(fmaf(-2.f, c[3], 1.f + w2v.w), 0.f);
        rmin[n] = fminf(rmin[n], fminf(fminf(d0, d1), fminf(d2, d3)));
        cmin[t][m][0] = fminf(cmin[t][m][0], d0);
        cmin[t][m][1] = fminf(cmin[t][m][1], d1);
        cmin[t][m][2] = fminf(cmin[t][m][2], d2);
        cmin[t][m][3] = fminf(cmin[t][m][3], d3);
      }
    }
  }
  // row-min: reduce across q (same x-row for equal r16)
#pragma unroll
  for (int mask = 16; mask <= 32; mask <<= 1)
#pragma unroll
    for (int n = 0; n < 4; ++n)
      rmin[n] = fminf(rmin[n], __shfl_xor(rmin[n], mask));
  if (q == 0) {
#pragma unroll
    for (int n = 0; n < 4; ++n)
      atomicMin(&rowmin_u[wx * 64 + n * 16 + r16], __float_as_uint(rmin[n]));
  }
  // col-min: reduce across r16 (same w-col for equal q)
#pragma unroll
  for (int mask = 1; mask <= 8; mask <<= 1)
#pragma unroll
    for (int t = 0; t < 2; ++t)
#pragma unroll
      for (int m = 0; m < 4; ++m)
#pragma unroll
        for (int j = 0; j < 4; ++j)
          cmin[t][m][j] = fminf(cmin[t][m][j], __shfl_xor(cmin[t][m][j], mask));
  if (r16 == 0) {
#pragma unroll
    for (int t = 0; t < 2; ++t)
#pragma unroll
      for (int m = 0; m < 4; ++m)
#pragma unroll
        for (int j = 0; j < 4; ++j)
          atomicMin(&colmin_u[t * 128 + ww * 64 + m * 16 + q * 4 + j],
                    __float_as_uint(cmin[t][m][j]));
  }
  __syncthreads();
  if (tid < 128) atomicMin(&rowmin_g[x0 + tid], rowmin_u[tid]);
  atomicMin(&colmin_g[w0 + tid], colmin_u[tid]);
}

// ---------------------------------------------------------------------------
// Combined reduce: bid<128 -> row mins chunk; bid>=128 -> col mins chunk.
// sqrt + fixed-order block sums (deterministic).
// ---------------------------------------------------------------------------
__global__ __launch_bounds__(256) void minsqrt_sum(const unsigned int* __restrict__ rmins,
                                                   const unsigned int* __restrict__ cmins,
                                                   float* __restrict__ rowsums,
                                                   float* __restrict__ colsums) {
  int bid = blockIdx.x;
  const unsigned int* src = (bid < 128) ? (rmins + bid * 256) : (cmins + (bid - 128) * 256);
  float s = sqrtf(__uint_as_float(src[threadIdx.x]));
#pragma unroll
  for (int mask = 1; mask < 64; mask <<= 1) s += __shfl_xor(s, mask);
  __shared__ float wsum[4];
  int wave = threadIdx.x >> 6, lane = threadIdx.x & 63;
  if (lane == 0) wsum[wave] = s;
  __syncthreads();
  if (threadIdx.x == 0) {
    float t = wsum[0] + wsum[1] + wsum[2] + wsum[3];
    if (bid < 128) rowsums[bid] = t; else colsums[bid - 128] = t;
  }
}

__global__ void finalize_kernel(const float* __restrict__ rowp, const float* __restrict__ colp,
                                const float* __restrict__ recon, const float* __restrict__ kl,
                                const float* __restrict__ mmd, float* __restrict__ out) {
  int lane = threadIdx.x;  // 64 threads
  float rs = rowp[lane] + rowp[lane + 64];
  float cs = (lane < 16) ? colp[lane] : 0.0f;
#pragma unroll
  for (int mask = 1; mask < 64; mask <<= 1) {
    rs += __shfl_xor(rs, mask);
    cs += __shfl_xor(cs, mask);
  }
  if (lane == 0) {
    out[OUT_CVAE] = recon[0] + 0.5f * kl[0] + mmd[0];
    out[OUT_PROT] = 0.5f * (rs / (float)N_ROWS) + 0.5f * (cs / (float)P_DIM);
  }
}

extern "C" void kernel_launch(void* const* d_in, const int* in_sizes, int n_in,
                              void* d_out, int out_size, void* d_ws, size_t ws_size,
                              hipStream_t stream) {
  const float* x     = (const float*)d_in[0];
  const float* W     = (const float*)d_in[1];
  const float* recon = (const float*)d_in[2];
  const float* kl    = (const float*)d_in[3];
  const float* mmd   = (const float*)d_in[4];
  float* out    = (float*)d_out;
  float* xn     = out;
  float* logits = out + OUT_LOGITS;

  char* ws = (char*)d_ws;
  unsigned short* Xbf = (unsigned short*)ws;                 // 33,554,432 B
  unsigned short* Wbf = (unsigned short*)(ws + 33554432);    //  4,194,304 B
  float* w2          = (float*)(ws + 37748736);              //     16,384 B
  unsigned int* rmg  = (unsigned int*)(ws + 37765120);       //    131,072 B (32768)
  unsigned int* cmg  = (unsigned int*)(ws + 37896192);       //     16,384 B (4096)
  float* rowsums     = (float*)(ws + 37912576);              //        512 B (128)
  float* colsums     = (float*)(ws + 37913088);              //         64 B (16)

  prep_kernel<<<8192 + 1024, 256, 0, stream>>>(x, W, xn, Xbf, Wbf, w2, rmg, cmg);
  gemm_fused<<<(N_ROWS / 128) * (P_DIM / 256), 256, 0, stream>>>(
      Wbf, Xbf, w2, logits, rmg, cmg);
  minsqrt_sum<<<144, 256, 0, stream>>>(rmg, cmg, rowsums, colsums);
  finalize_kernel<<<1, 64, 0, stream>>>(rowsums, colsums, recon, kl, mmd, out);
}

// Round 21
// 209.224 us; speedup vs baseline: 1.4188x; 1.2778x over previous
//
#include <hip/hip_runtime.h>

#define N_ROWS 32768
#define D_DIM  512
#define P_DIM  4096

#define OUT_LOGITS (32768LL * 512)
#define OUT_CVAE   (OUT_LOGITS + 32768LL * 4096)
#define OUT_PROT   (OUT_CVAE + 1)

typedef __attribute__((ext_vector_type(4))) float f32x4;

__device__ __forceinline__ void gload16(const void* g, void* l) {
  __builtin_amdgcn_global_load_lds((const __attribute__((address_space(1))) void*)g,
                                   (__attribute__((address_space(3))) void*)l,
                                   16, 0, 0);
}

// ---------------------------------------------------------------------------
// Combined prep: blocks [0,8192) = X path (L2-norm, xn fp32 NT stores, fp8
// copy, min-array init); [8192,9216) = W path (|row|^2 + fp8 copy).
// fp8(e4m3, OCP) fragment-major 128-row-tile layout — same index formula as
// the verified bf16 layout, byte-granular:
// byte[(tile*16+kt)*4096 + (fr*64 + kq*16 + r)*8 + e], tile=row>>7,
// fr=(row>>4)&7, r=row&15; lane j holds k=j*8..j*8+7 (kt=j>>2, kq=j&3).
// ---------------------------------------------------------------------------
__global__ __launch_bounds__(256) void prep_kernel(const float* __restrict__ x,
                                                   const float* __restrict__ W,
                                                   float* __restrict__ xn,
                                                   unsigned char* __restrict__ Xq,
                                                   unsigned char* __restrict__ Wq,
                                                   float* __restrict__ w2,
                                                   unsigned int* __restrict__ rmg,
                                                   unsigned int* __restrict__ cmg) {
  const int bid = blockIdx.x;
  const int isX = (bid < 8192);
  if (isX) {
    if (bid < 128)      rmg[bid * 256 + threadIdx.x] = 0x7F800000u;
    else if (bid < 144) cmg[(bid - 128) * 256 + threadIdx.x] = 0x7F800000u;
  }
  int wave = threadIdx.x >> 6, lane = threadIdx.x & 63;
  int row  = (isX ? bid : (bid - 8192)) * 4 + wave;
  const float* p = (isX ? x : W) + (size_t)row * D_DIM + lane * 8;
  float4 v0 = *(const float4*)p;
  float4 v1 = *(const float4*)(p + 4);
  float ss = v0.x*v0.x + v0.y*v0.y + v0.z*v0.z + v0.w*v0.w
           + v1.x*v1.x + v1.y*v1.y + v1.z*v1.z + v1.w*v1.w;
#pragma unroll
  for (int m = 1; m < 64; m <<= 1) ss += __shfl_xor(ss, m);
  if (isX) {
    float rinv = 1.0f / fmaxf(sqrtf(ss), 1e-12f);
    v0.x *= rinv; v0.y *= rinv; v0.z *= rinv; v0.w *= rinv;
    v1.x *= rinv; v1.y *= rinv; v1.z *= rinv; v1.w *= rinv;
    f32x4* qp = (f32x4*)(xn + (size_t)row * D_DIM + lane * 8);
    f32x4 a0 = {v0.x, v0.y, v0.z, v0.w};
    f32x4 a1 = {v1.x, v1.y, v1.z, v1.w};
    __builtin_nontemporal_store(a0, qp);
    __builtin_nontemporal_store(a1, qp + 1);
  } else {
    if (lane == 0) w2[row] = ss;
  }
  // pack 8 floats -> 8 fp8 e4m3 bytes
  unsigned w0b = 0, w1b = 0;
  w0b = __builtin_amdgcn_cvt_pk_fp8_f32(v0.x, v0.y, w0b, 0);
  w0b = __builtin_amdgcn_cvt_pk_fp8_f32(v0.z, v0.w, w0b, 1);
  w1b = __builtin_amdgcn_cvt_pk_fp8_f32(v1.x, v1.y, w1b, 0);
  w1b = __builtin_amdgcn_cvt_pk_fp8_f32(v1.z, v1.w, w1b, 1);
  uint2 b; b.x = w0b; b.y = w1b;
  int tile = row >> 7, fr = (row >> 4) & 7, r = row & 15;
  size_t dst = (size_t)(tile * 16 + (lane >> 2)) * 4096
             + (size_t)((fr * 64 + (lane & 3) * 16 + r) * 8);
  *(uint2*)((isX ? Xq : Wq) + dst) = b;
}

// ---------------------------------------------------------------------------
// 128x128-tile fp8 GEMM — R18 structure with HALVED feed bytes everywhere:
// mfma_f32_16x16x32_fp8_fp8 (same shape/rate/C-layout as bf16, 1 B/elem).
// W-frags (512 B each) direct from XCD-L2 (panel now 256 KB); X staged in
// LDS 3-buf (3 x 4 KB, 1 gload16/thread/step), counted vmcnt(1);
// 4 blocks/CU; one s_barrier/step; setprio; NT scattered stores (best
// measured); fused d2 -> global atomicMin (deterministic).
// Per-CU feed/step: LDS 32r+16w KB -> 48 KB (was 96), L1 32 KB (was 64).
// ---------------------------------------------------------------------------
__global__ __launch_bounds__(256, 4) void gemm_fused(
    const unsigned char* __restrict__ Wq, const unsigned char* __restrict__ Xq,
    const float* __restrict__ w2, float* __restrict__ Cout,
    unsigned int* __restrict__ rowmin_g, unsigned int* __restrict__ colmin_g) {
  __shared__ __align__(16) unsigned char SB[3][4096];   // x tile 128x32 fp8
  __shared__ unsigned int rowmin_u[128];                // per x-row
  __shared__ unsigned int colmin_u[128];                // per w-col

  const int tid = threadIdx.x;
  const int wave = tid >> 6, lane = tid & 63;
  const int q = lane >> 4, r16 = lane & 15;
  const int ww = wave >> 1, wx = wave & 1;

  const int b = blockIdx.x;
  const int tw = (b & 7) * 4 + ((b >> 3) & 3);   // 0..31 (XCD-pinned W column)
  const int tx = b >> 5;                         // 0..255
  const int w0 = tw * 128, x0 = tx * 128;

  if (tid < 128) { rowmin_u[tid] = 0x7F800000u; colmin_u[tid] = 0x7F800000u; }

  const unsigned char* Wg = Wq + (size_t)(tw * 16) * 4096;
  const unsigned char* Xg = Xq + (size_t)(tx * 16) * 4096;

  f32x4 acc[4][4];
#pragma unroll
  for (int m = 0; m < 4; ++m)
#pragma unroll
    for (int n = 0; n < 4; ++n) acc[m][n] = (f32x4){0.f, 0.f, 0.f, 0.f};

  auto stg = [&](int kt, int bu) {   // 1 gload16/thread: 4 KB X tile
    gload16(Xg + (size_t)kt * 4096 + tid * 16, &SB[bu][0] + tid * 16);
  };

  stg(0, 0);
  stg(1, 1);

#pragma unroll
  for (int kt = 0; kt < 16; ++kt) {
    const int cur = kt % 3;
    if (kt < 15) { asm volatile("s_waitcnt vmcnt(1)" ::: "memory"); }   // stg(kt) done
    else         { asm volatile("s_waitcnt vmcnt(0)" ::: "memory"); }
    __builtin_amdgcn_s_barrier();

    if (kt < 14) stg(kt + 2, (kt + 2) % 3);   // buffer last read at kt-1: WAR-safe

    long af[4], bf[4];
#pragma unroll
    for (int m = 0; m < 4; ++m)          // W-frags straight from L1/L2 (8 B/lane)
      af[m] = *(const long*)(Wg + (size_t)kt * 4096 + ((ww * 4 + m) * 64 + lane) * 8);
#pragma unroll
    for (int n = 0; n < 4; ++n)
      bf[n] = *(const long*)(&SB[cur][0] + ((wx * 4 + n) * 64 + lane) * 8);

    __builtin_amdgcn_s_setprio(1);
#pragma unroll
    for (int m = 0; m < 4; ++m)
#pragma unroll
      for (int n = 0; n < 4; ++n)
        acc[m][n] = __builtin_amdgcn_mfma_f32_16x16x32_fp8_fp8(af[m], bf[n], acc[m][n], 0, 0, 0);
    __builtin_amdgcn_s_setprio(0);
  }

  // ---- epilogue: NT float4 stores + fused d2 mins (R18 verbatim) ----
  float rmin[4];                      // per n (x-rows)
  float cmin[4][4];                   // per m,j (w-cols)
#pragma unroll
  for (int n = 0; n < 4; ++n) rmin[n] = 1e30f;
#pragma unroll
  for (int m = 0; m < 4; ++m)
#pragma unroll
    for (int j = 0; j < 4; ++j) cmin[m][j] = 1e30f;

  const float* w2p = w2 + w0 + ww * 64;
#pragma unroll
  for (int m = 0; m < 4; ++m) {
    float4 w2v = *(const float4*)(w2p + m * 16 + q * 4);
    const size_t wcol = (size_t)(w0 + ww * 64 + m * 16 + q * 4);
#pragma unroll
    for (int n = 0; n < 4; ++n) {
      f32x4 c = acc[m][n];
      int xr = x0 + wx * 64 + n * 16 + r16;
      __builtin_nontemporal_store(c, (f32x4*)&Cout[(size_t)xr * P_DIM + wcol]);
      float d0 = fmaxf(fmaf(-2.f, c[0], 1.f + w2v.x), 0.f);
      float d1 = fmaxf(fmaf(-2.f, c[1], 1.f + w2v.y), 0.f);
      float d2 = fmaxf(fmaf(-2.f, c[2], 1.f + w2v.z), 0.f);
      float d3 = fmaxf(fmaf(-2.f, c[3], 1.f + w2v.w), 0.f);
      rmin[n] = fminf(rmin[n], fminf(fminf(d0, d1), fminf(d2, d3)));
      cmin[m][0] = fminf(cmin[m][0], d0);
      cmin[m][1] = fminf(cmin[m][1], d1);
      cmin[m][2] = fminf(cmin[m][2], d2);
      cmin[m][3] = fminf(cmin[m][3], d3);
    }
  }
  // row-min: reduce across q (same x-row for equal r16)
#pragma unroll
  for (int mask = 16; mask <= 32; mask <<= 1)
#pragma unroll
    for (int n = 0; n < 4; ++n)
      rmin[n] = fminf(rmin[n], __shfl_xor(rmin[n], mask));
  if (q == 0) {
#pragma unroll
    for (int n = 0; n < 4; ++n)
      atomicMin(&rowmin_u[wx * 64 + n * 16 + r16], __float_as_uint(rmin[n]));
  }
  // col-min: reduce across r16 (same w-col for equal q)
#pragma unroll
  for (int mask = 1; mask <= 8; mask <<= 1)
#pragma unroll
    for (int m = 0; m < 4; ++m)
#pragma unroll
      for (int j = 0; j < 4; ++j)
        cmin[m][j] = fminf(cmin[m][j], __shfl_xor(cmin[m][j], mask));
  if (r16 == 0) {
#pragma unroll
    for (int m = 0; m < 4; ++m)
#pragma unroll
      for (int j = 0; j < 4; ++j)
        atomicMin(&colmin_u[ww * 64 + m * 16 + q * 4 + j], __float_as_uint(cmin[m][j]));
  }
  __syncthreads();
  if (tid < 128) atomicMin(&rowmin_g[x0 + tid], rowmin_u[tid]);
  else           atomicMin(&colmin_g[w0 + (tid - 128)], colmin_u[tid - 128]);
}

// ---------------------------------------------------------------------------
// Combined reduce: bid<128 -> row mins chunk; bid>=128 -> col mins chunk.
// sqrt + fixed-order block sums (deterministic).
// ---------------------------------------------------------------------------
__global__ __launch_bounds__(256) void minsqrt_sum(const unsigned int* __restrict__ rmins,
                                                   const unsigned int* __restrict__ cmins,
                                                   float* __restrict__ rowsums,
                                                   float* __restrict__ colsums) {
  int bid = blockIdx.x;
  const unsigned int* src = (bid < 128) ? (rmins + bid * 256) : (cmins + (bid - 128) * 256);
  float s = sqrtf(__uint_as_float(src[threadIdx.x]));
#pragma unroll
  for (int mask = 1; mask < 64; mask <<= 1) s += __shfl_xor(s, mask);
  __shared__ float wsum[4];
  int wave = threadIdx.x >> 6, lane = threadIdx.x & 63;
  if (lane == 0) wsum[wave] = s;
  __syncthreads();
  if (threadIdx.x == 0) {
    float t = wsum[0] + wsum[1] + wsum[2] + wsum[3];
    if (bid < 128) rowsums[bid] = t; else colsums[bid - 128] = t;
  }
}

__global__ void finalize_kernel(const float* __restrict__ rowp, const float* __restrict__ colp,
                                const float* __restrict__ recon, const float* __restrict__ kl,
                                const float* __restrict__ mmd, float* __restrict__ out) {
  int lane = threadIdx.x;  // 64 threads
  float rs = rowp[lane] + rowp[lane + 64];
  float cs = (lane < 16) ? colp[lane] : 0.0f;
#pragma unroll
  for (int mask = 1; mask < 64; mask <<= 1) {
    rs += __shfl_xor(rs, mask);
    cs += __shfl_xor(cs, mask);
  }
  if (lane == 0) {
    out[OUT_CVAE] = recon[0] + 0.5f * kl[0] + mmd[0];
    out[OUT_PROT] = 0.5f * (rs / (float)N_ROWS) + 0.5f * (cs / (float)P_DIM);
  }
}

extern "C" void kernel_launch(void* const* d_in, const int* in_sizes, int n_in,
                              void* d_out, int out_size, void* d_ws, size_t ws_size,
                              hipStream_t stream) {
  const float* x     = (const float*)d_in[0];
  const float* W     = (const float*)d_in[1];
  const float* recon = (const float*)d_in[2];
  const float* kl    = (const float*)d_in[3];
  const float* mmd   = (const float*)d_in[4];
  float* out    = (float*)d_out;
  float* xn     = out;
  float* logits = out + OUT_LOGITS;

  char* ws = (char*)d_ws;
  unsigned char* Xq  = (unsigned char*)ws;                   // 16,777,216 B
  unsigned char* Wq  = (unsigned char*)(ws + 16777216);      //  2,097,152 B
  float* w2          = (float*)(ws + 18874368);              //     16,384 B
  unsigned int* rmg  = (unsigned int*)(ws + 18890752);       //    131,072 B (32768)
  unsigned int* cmg  = (unsigned int*)(ws + 19021824);       //     16,384 B (4096)
  float* rowsums     = (float*)(ws + 19038208);              //        512 B (128)
  float* colsums     = (float*)(ws + 19038720);              //         64 B (16)

  prep_kernel<<<8192 + 1024, 256, 0, stream>>>(x, W, xn, Xq, Wq, w2, rmg, cmg);
  gemm_fused<<<(N_ROWS / 128) * (P_DIM / 128), 256, 0, stream>>>(
      Wq, Xq, w2, logits, rmg, cmg);
  minsqrt_sum<<<144, 256, 0, stream>>>(rmg, cmg, rowsums, colsums);
  finalize_kernel<<<1, 64, 0, stream>>>(rowsums, colsums, recon, kl, mmd, out);
}